// Round 4
// baseline (178.951 us; speedup 1.0000x reference)
//
#include <hip/hip_runtime.h>
#include <hip/hip_bf16.h>

#define B_  2
#define T_  2048
#define D_  1024
#define H_  16
#define KH_ 4
#define DH_ 64

typedef __attribute__((ext_vector_type(8))) short bf16x8;   // 8 bf16 = 4 VGPRs
typedef __attribute__((ext_vector_type(4))) float f32x4;

// log2(e)/8: folded into Q at projection time so softmax is p = exp2(s_raw).
#define QSCALE 0.18033688011112043f

// single-instruction v_exp_f32 if available (OCML exp2f is ~10 instrs)
#if defined(__has_builtin)
#  if __has_builtin(__builtin_amdgcn_exp2f)
#    define EXP2F(x) __builtin_amdgcn_exp2f(x)
#  endif
#endif
#ifndef EXP2F
#  define EXP2F(x) exp2f(x)
#endif

// fp32 -> bf16 RNE (scalar, for prep paths where cvt_pk doesn't fit)
__device__ __forceinline__ unsigned short f2bf(float f) {
  union { float f; unsigned int u; } v; v.f = f;
  return (unsigned short)((v.u + 0x7FFFu + ((v.u >> 16) & 1u)) >> 16);
}
// packed fp32x2 -> bf16x2 via v_cvt_pk_bf16_f32 (1 VALU op)
__device__ __forceinline__ unsigned int pk2(float a, float b) {
  union { __hip_bfloat162 h2; unsigned int u; } v;
  v.h2 = __float22bfloat162_rn(make_float2(a, b));
  return v.u;
}

// async global->LDS, 16B per lane. LDS dest = wave-uniform base + lane*16;
// global source is per-lane (pre-swizzled source pattern, m173/rule #21).
__device__ __forceinline__ void g2l16(const void* g, void* l) {
  __builtin_amdgcn_global_load_lds(
      (const __attribute__((address_space(1))) void*)g,
      (__attribute__((address_space(3))) void*)l, 16, 0, 0);
}

// d-slot permutation: slot(d) = (d&15)*4 + (d>>4). Applied consistently to
// Q/K d-dims (QK contraction invariant), att per-head d-dim + WoT k-rows
// (outproj contraction invariant). Exact.
//
// V key-slot permutation (attn swapped-QK in-register P): slot g (0..63)
// holds key tok(g) with bit map  tok5<-g5, tok4<-g2, tok3:2<-g4:3,
// tok1:0<-g1:0.  This makes the PV A-operand buildable from each lane's OWN
// exp'd QK outputs (no cross-lane exchange, no P LDS bounce).

// ---------------------------------------------------------------------------
// Merged prep (one launch): x->bf16, Wqkv->WT (bf16 transposed),
// Wo->WoT (bf16 transposed, k-rows sigma-permuted per head), RoPE table.
// ---------------------------------------------------------------------------
__global__ __launch_bounds__(256) void prep_kernel(
    const float* __restrict__ x,  const float* __restrict__ Wq,
    const float* __restrict__ Wk, const float* __restrict__ Wv,
    const float* __restrict__ Wo,
    short* __restrict__ xb, short* __restrict__ WT, short* __restrict__ WoT,
    float2* __restrict__ tbl) {
  __shared__ short Ts[64 * 72];
  const int bid = blockIdx.x, tid = threadIdx.x;

  if (bid < 2048) {                             // ---- x -> bf16
    const size_t i8 = ((size_t)bid * 256 + tid) * 8;
    const float4 a = *(const float4*)&x[i8];
    const float4 b = *(const float4*)&x[i8 + 4];
    uint4 p; p.x = pk2(a.x, a.y); p.y = pk2(a.z, a.w);
    p.z = pk2(b.x, b.y); p.w = pk2(b.z, b.w);
    *(uint4*)&xb[i8] = p;
  } else if (bid < 2688) {                      // ---- WT / WoT transpose
    const bool isW = bid < 2432;
    const int idx = isW ? (bid - 2048) : (bid - 2432);
    const int n0 = (idx >> 4) * 64, k0 = (idx & 15) * 64;
    const float* src; int ncols, c0; short* dst;
    if (isW) {
      dst = WT;
      if (n0 < 1024)      { src = Wq; ncols = 1024; c0 = n0; }
      else if (n0 < 1280) { src = Wk; ncols = 256;  c0 = n0 - 1024; }
      else                { src = Wv; ncols = 256;  c0 = n0 - 1280; }
    } else { dst = WoT; src = Wo; ncols = 1024; c0 = n0; }
    for (int i = tid; i < 1024; i += 256) {
      const int kr = i >> 4, c4 = (i & 15) << 2;
      // WoT k-rows permuted: slot(kr) = (kr&15)*4 + (kr>>4) (k0 is 64-aligned
      // = one head's range, so per-head sigma).
      const int kc = isW ? kr : ((kr & 15) * 4 + (kr >> 4));
      const float4 w = *(const float4*)&src[(size_t)(k0 + kr) * ncols + c0 + c4];
      Ts[(c4 + 0) * 72 + kc] = (short)f2bf(w.x);
      Ts[(c4 + 1) * 72 + kc] = (short)f2bf(w.y);
      Ts[(c4 + 2) * 72 + kc] = (short)f2bf(w.z);
      Ts[(c4 + 3) * 72 + kc] = (short)f2bf(w.w);
    }
    __syncthreads();
    for (int c = tid; c < 512; c += 256) {
      const int nr = c >> 3, c8 = (c & 7) * 8;
      *(bf16x8*)&dst[(size_t)(n0 + nr) * 1024 + k0 + c8] =
          *(const bf16x8*)&Ts[nr * 72 + c8];
    }
  } else {                                      // ---- RoPE table
    const int e = (bid - 2688) * 256 + tid;     // 65536 entries
    const int t = e >> 5, i2 = e & 31;
    const float freq = exp2f(-(float)(2 * i2) * (18.931568569324174f / 64.0f));
    float sn, cs; sincosf((float)t * freq, &sn, &cs);
    tbl[e] = make_float2(cs, sn);
  }
}

// ---------------------------------------------------------------------------
// Kernel 1: QKV projection, 128x64 tiles, BK=128 (8 k-iters, 32 MFMA per
// barrier-pair per wave), grid 768 1-D blocks (3/CU), XCD-chunked mapping.
// Staging via global_load_lds width=16 (m97 pattern). LDS linear stride 128
// with XOR block swizzle (source-side pre-swizzle, rule #21).
// nt<16: Q (RoPE + QSCALE fold). 16..19: K (RoPE). 20..23: V (LDS-bounce
// transpose -> (b,kh,d,t), key slots permuted per attn's in-register-P map).
// [UNCHANGED from round 3]
// ---------------------------------------------------------------------------
__global__ __launch_bounds__(256) void qkv_mfma_kernel(
    const short* __restrict__ xb, const short* __restrict__ WT,
    const float2* __restrict__ tbl,
    short* __restrict__ qo, short* __restrict__ ko, short* __restrict__ vt) {
  __shared__ short Xs[128 * 128];
  __shared__ short Wt[64 * 128];
  const int tid = threadIdx.x;
  const int lane = tid & 63, w = tid >> 6;
  const int lm = lane & 15, quad = lane >> 4;
  const int lr = lane >> 4;                     // row within 4-row LDS chunk
  const int lb = lane & 15;                     // dest 16B block within row
  // XCD-chunked decode: 768 = 8 XCDs x (4 m x 24 n)
  const int bid = blockIdx.x;
  const int xcd = bid & 7, slot = bid >> 3;     // slot 0..95
  const int mt = xcd * 4 + (slot & 3);          // 0..31
  const int nt = slot >> 2;                     // 0..23
  const int m0 = mt * 128;
  const int n0 = nt * 64;                       // 0..1472

  f32x4 acc[2][4];
  #pragma unroll
  for (int sm = 0; sm < 2; ++sm)
    #pragma unroll
    for (int ct = 0; ct < 4; ++ct) acc[sm][ct] = (f32x4){0.f, 0.f, 0.f, 0.f};

  for (int kt = 0; kt < 8; ++kt) {
    __syncthreads();                            // prior tile's LDS reads done
    #pragma unroll
    for (int u = 0; u < 8; ++u) {               // Xs chunk w*8+u (4 rows/1KB)
      const int r = (w * 8 + u) * 4 + lr;
      const int sb = lb ^ (r & 7);              // inverse-swizzled source blk
      g2l16(&xb[(size_t)(m0 + r) * 1024 + kt * 128 + sb * 8],
            &Xs[(w * 8 + u) * 512]);
    }
    #pragma unroll
    for (int u = 0; u < 4; ++u) {               // Wt chunk w*4+u
      const int r = (w * 4 + u) * 4 + lr;
      const int sb = lb ^ (r & 7);
      g2l16(&WT[(size_t)(n0 + r) * 1024 + kt * 128 + sb * 8],
            &Wt[(w * 4 + u) * 512]);
    }
    asm volatile("s_waitcnt vmcnt(0)" ::: "memory");
    __syncthreads();                            // staged tile visible
    #pragma unroll
    for (int s = 0; s < 4; ++s) {               // 4 k-steps of 32
      bf16x8 bfr[4];
      #pragma unroll
      for (int ct = 0; ct < 4; ++ct)
        bfr[ct] = *(const bf16x8*)&Wt[(ct * 16 + lm) * 128 +
                                      (((s * 4 + quad) ^ (lm & 7)) << 3)];
      #pragma unroll
      for (int sm = 0; sm < 2; ++sm) {
        const bf16x8 a = *(const bf16x8*)&Xs[(w * 32 + sm * 16 + lm) * 128 +
                                             (((s * 4 + quad) ^ (lm & 7)) << 3)];
        #pragma unroll
        for (int ct = 0; ct < 4; ++ct)
          acc[sm][ct] =
              __builtin_amdgcn_mfma_f32_16x16x32_bf16(a, bfr[ct], acc[sm][ct], 0, 0, 0);
      }
    }
  }

  if (n0 < 1280) {                              // ---- Q or K: RoPE + b64 store
    const bool isQ = n0 < 1024;
    short* outp = isQ ? qo : ko;
    const int base = isQ ? n0 : n0 - 1024;
    const int nh = isQ ? H_ : KH_;
    const int hh = base >> 6;                   // tile width 64 = one head
    const float post = isQ ? QSCALE : 1.0f;     // fold softmax scale into Q
    #pragma unroll
    for (int sm = 0; sm < 2; ++sm)
      #pragma unroll
      for (int r = 0; r < 4; ++r) {
        const int row = m0 + w * 32 + sm * 16 + quad * 4 + r;
        const int b = row >> 11, t = row & 2047;
        float v4[4];
        #pragma unroll
        for (int ct = 0; ct < 4; ++ct) {
          float val = acc[sm][ct][r];
          const float other = __shfl_xor(val, 1);
          const int ci = ct * 16 + lm;          // d within head
          const float2 cs = tbl[t * 32 + (ci >> 1)];
          val = ((ci & 1) == 0) ? (val * cs.x - other * cs.y)
                                : (val * cs.x + other * cs.y);
          v4[ct] = val * post;
        }
        // d ct*16+lm -> slot lm*4+ct: one b64 store of 4 consecutive slots
        uint2 st; st.x = pk2(v4[0], v4[1]); st.y = pk2(v4[2], v4[3]);
        *(uint2*)&outp[((size_t)(b * nh + hh) * T_ + t) * DH_ + lm * 4] = st;
      }
  } else {                                      // ---- V: LDS-bounce transpose
    __syncthreads();                            // done with Xs as GEMM tile
    #pragma unroll
    for (int sm = 0; sm < 2; ++sm)
      #pragma unroll
      for (int r = 0; r < 4; ++r)
        #pragma unroll
        for (int ct = 0; ct < 4; ++ct)
          Xs[(w * 32 + sm * 16 + quad * 4 + r) * 72 + ct * 16 + lm] =
              (short)f2bf(acc[sm][ct][r]);      // Xs[t][d], stride 72 region
    __syncthreads();
    const int kh = (n0 - 1280) >> 6;
    const int b = m0 >> 11, t0 = m0 & 2047;
    short* vb = vt + (size_t)(b * KH_ + kh) * DH_ * T_;
    for (int c = tid; c < 1024; c += 256) {     // 64 d-rows x 16 chunks of 8 slots
      const int d = c >> 4, c8 = (c & 15) * 8;
      short tmp[8];
      #pragma unroll
      for (int j = 0; j < 8; ++j) {
        const int s = c8 + j, sg = s & 63;      // slot s -> token within group
        // tok bits: b5<-g5, b4<-g2, b3:2<-g4:3, b1:0<-g1:0 (in-reg P map)
        const int tok = (s & 64) | (sg & 35) | (((sg >> 2) & 1) << 4) |
                        (((sg >> 3) & 3) << 2);
        tmp[j] = Xs[tok * 72 + d];
      }
      *(bf16x8*)&vb[(size_t)d * T_ + t0 + c8] = *(bf16x8*)tmp;
    }
  }
}

// ---------------------------------------------------------------------------
// Kernel 2: causal flash attention, swapped-QK in-register-P, TWO HEADS per
// block. Heads 2hp,2hp+1 share kh (n_rep=4): K/V staged once, every Ks/Vts
// ds_read_b128 feeds TWO MFMAs (one per head) -> per-useful-FLOP LDS read
// traffic halves (was 4 waves x identical w-independent rows = 4x redundant;
// this was the largest pipe cost, ~16.6us of 43 at the 69TB/s LDS ceiling).
// Each wave carries two independent QK->exp->PV chains -> in-wave ILP
// replaces the wave-level phase diversity lost going 1024->512 blocks.
// Grid 512 = exactly 2/CU, all resident at t=0; qt interleave gives every
// CU the pair {31-q, q} = constant 33 tile-steps. Diagonal tiles skip ct>w
// QK-MFMAs and 2s>w PV-chunks (wave-uniform). Row-sum via MFMA ones-column;
// register prefetch for K/V; s_setprio(1) around MFMA clusters (T5).
// Per-head softmax/mask/layout logic IDENTICAL to the round-2/3 verified
// kernel — only duplicated per head.
// ---------------------------------------------------------------------------
__global__ __launch_bounds__(256, 2) void attn_mfma_kernel(
    const short* __restrict__ q, const short* __restrict__ k,
    const short* __restrict__ vt, short* __restrict__ att) {
  __shared__ short Ks[128 * 72];
  __shared__ short Vts[64 * 136];               // [d][slot 0..127]

  const int bx = blockIdx.x;                    // 0..511
  const int jj = bx & 255, c2 = bx >> 8;        // c2 0..1
  int qt = (c2 & 1) ? (jj >> 3) : (31 - (jj >> 3));   // heavy-first in chunk 0
  const int hb = (jj & 7) | (c2 << 3);          // 0..15 = hp x b
  const int hp = hb >> 1, b = hb & 1;
  const int h0 = hp * 2, h1 = h0 + 1;
  const int kh = h0 >> 2;                       // n_rep = 4
  const int tid = threadIdx.x;
  const int lane = tid & 63, w = tid >> 6;
  const int lm = lane & 15, quad = lane >> 4;
  const int q0 = qt * 64;

  const short* qb0 = q + (size_t)(b * H_ + h0) * T_ * DH_;
  const short* qb1 = qb0 + (size_t)T_ * DH_;    // h1 = h0+1 contiguous
  const short* kb = k + (size_t)(b * KH_ + kh) * T_ * DH_;
  const short* vb = vt + (size_t)(b * KH_ + kh) * DH_ * T_;

  bf16x8 ones;
  #pragma unroll
  for (int i = 0; i < 8; ++i) ones[i] = (short)0x3F80;  // bf16 1.0

  bf16x8 aq0[2], aq1[2];                        // kt-invariant Q fragments
  #pragma unroll
  for (int s = 0; s < 2; ++s) {                 // direct global load (no LDS)
    const size_t off = (size_t)(q0 + w * 16 + lm) * 64 + s * 32 + quad * 8;
    aq0[s] = *(const bf16x8*)&qb0[off];
    aq1[s] = *(const bf16x8*)&qb1[off];
  }

  bf16x8 pk[4], pv[4];
  #pragma unroll
  for (int u = 0; u < 4; ++u) {                 // preload r2=0 (128 keys)
    const int c = tid + u * 256;
    const int row = c >> 3, c8 = (c & 7) * 8;
    pk[u] = *(const bf16x8*)&kb[(size_t)row * 64 + c8];
    const int d = c >> 4, c16 = (c & 15) * 8;
    pv[u] = *(const bf16x8*)&vb[(size_t)d * T_ + c16];
  }

  f32x4 oacc0[4], oacc1[4], lacc0, lacc1;
  #pragma unroll
  for (int i = 0; i < 4; ++i) {
    oacc0[i] = (f32x4){0.f, 0.f, 0.f, 0.f};
    oacc1[i] = (f32x4){0.f, 0.f, 0.f, 0.f};
  }
  lacc0 = (f32x4){0.f, 0.f, 0.f, 0.f};
  lacc1 = (f32x4){0.f, 0.f, 0.f, 0.f};

  // one 64-key tile-step (j selects which staged half; diag wave-uniform)
  auto step = [&](int j, bool diag) {
    f32x4 sacc0[4], sacc1[4];
    #pragma unroll
    for (int i = 0; i < 4; ++i) {
      sacc0[i] = (f32x4){0.f, 0.f, 0.f, 0.f};
      sacc1[i] = (f32x4){0.f, 0.f, 0.f, 0.f};
    }
    __builtin_amdgcn_s_setprio(1);
    #pragma unroll
    for (int s2 = 0; s2 < 2; ++s2) {
      #pragma unroll
      for (int ct = 0; ct < 4; ++ct) {
        if (diag && ct > w) continue;           // fully-masked block, skip
        const bf16x8 bb =
            *(const bf16x8*)&Ks[(j * 64 + ct * 16 + lm) * 72 + s2 * 32 + quad * 8];
        // swapped operands: D[key][q], q = lane&15; one LDS read, two heads
        sacc0[ct] = __builtin_amdgcn_mfma_f32_16x16x32_bf16(bb, aq0[s2], sacc0[ct], 0, 0, 0);
        sacc1[ct] = __builtin_amdgcn_mfma_f32_16x16x32_bf16(bb, aq1[s2], sacc1[ct], 0, 0, 0);
      }
    }
    __builtin_amdgcn_s_setprio(0);
    // in-lane softmax: sacc[ct][r] = P[key ct*16+quad*4+r][q w*16+lm]
    unsigned int pd0[4][2], pd1[4][2];
    #pragma unroll
    for (int ct = 0; ct < 4; ++ct) {
      float p0[4], p1[4];
      #pragma unroll
      for (int r = 0; r < 4; ++r) {
        float e0, e1;
        if (diag && ct > w) { e0 = 0.f; e1 = 0.f; }  // block above diagonal
        else {
          e0 = EXP2F(sacc0[ct][r]);
          e1 = EXP2F(sacc1[ct][r]);
          if (diag && ct == w && (quad * 4 + r) > lm) { e0 = 0.f; e1 = 0.f; }
        }
        p0[r] = e0; p1[r] = e1;
      }
      pd0[ct][0] = pk2(p0[0], p0[1]); pd0[ct][1] = pk2(p0[2], p0[3]);
      pd1[ct][0] = pk2(p1[0], p1[1]); pd1[ct][1] = pk2(p1[2], p1[3]);
    }
    __builtin_amdgcn_s_setprio(1);
    #pragma unroll
    for (int s2 = 0; s2 < 2; ++s2) {
      if (diag && 2 * s2 > w) continue;         // both ct' blocks masked
      union { bf16x8 v; unsigned int u[4]; } pa0, pa1;
      pa0.u[0] = pd0[2 * s2][0];     pa0.u[1] = pd0[2 * s2][1];
      pa0.u[2] = pd0[2 * s2 + 1][0]; pa0.u[3] = pd0[2 * s2 + 1][1];
      pa1.u[0] = pd1[2 * s2][0];     pa1.u[1] = pd1[2 * s2][1];
      pa1.u[2] = pd1[2 * s2 + 1][0]; pa1.u[3] = pd1[2 * s2 + 1][1];
      lacc0 = __builtin_amdgcn_mfma_f32_16x16x32_bf16(pa0.v, ones, lacc0, 0, 0, 0);
      lacc1 = __builtin_amdgcn_mfma_f32_16x16x32_bf16(pa1.v, ones, lacc1, 0, 0, 0);
      #pragma unroll
      for (int ct = 0; ct < 4; ++ct) {
        const bf16x8 vfr = *(const bf16x8*)&Vts[(ct * 16 + lm) * 136 +
                                                j * 64 + s2 * 32 + quad * 8];
        // one LDS read, two heads
        oacc0[ct] = __builtin_amdgcn_mfma_f32_16x16x32_bf16(pa0.v, vfr, oacc0[ct], 0, 0, 0);
        oacc1[ct] = __builtin_amdgcn_mfma_f32_16x16x32_bf16(pa1.v, vfr, oacc1[ct], 0, 0, 0);
      }
    }
    __builtin_amdgcn_s_setprio(0);
  };

  auto stage = [&](int r2) {
    __syncthreads();                            // prior K/V LDS reads done
    #pragma unroll
    for (int u = 0; u < 4; ++u) {
      const int c = tid + u * 256;
      const int row = c >> 3, c8 = (c & 7) * 8;
      *(bf16x8*)&Ks[row * 72 + c8] = pk[u];
      const int d = c >> 4, c16 = (c & 15) * 8;
      *(bf16x8*)&Vts[d * 136 + c16] = pv[u];
    }
    __syncthreads();
    const int r2n = (r2 + 2 <= qt) ? (r2 + 2) : r2;   // prefetch next pair
    #pragma unroll
    for (int u = 0; u < 4; ++u) {
      const int c = tid + u * 256;
      const int row = c >> 3, c8 = (c & 7) * 8;
      pk[u] = *(const bf16x8*)&kb[(size_t)(r2n * 64 + row) * 64 + c8];
      const int d = c >> 4, c16 = (c & 15) * 8;
      pv[u] = *(const bf16x8*)&vb[(size_t)d * T_ + r2n * 64 + c16];
    }
  };

  int r2 = 0;
  for (; r2 + 1 <= qt; r2 += 2) {               // full pairs only
    stage(r2);
    step(0, false);                             // never diagonal
    step(1, r2 + 1 == qt);                      // diagonal only on last pair
  }
  if (r2 == qt) {                               // peeled final step (even qt)
    stage(r2);
    step(0, true);
  }

  #pragma unroll
  for (int r = 0; r < 4; ++r) {
    const int qrow = q0 + w * 16 + quad * 4 + r;
    // d ct*16+lm -> slot lm*4+ct (WoT k-rows match): one b64 store per head
    const float inv0 = 1.f / lacc0[r];
    uint2 st;
    st.x = pk2(oacc0[0][r] * inv0, oacc0[1][r] * inv0);
    st.y = pk2(oacc0[2][r] * inv0, oacc0[3][r] * inv0);
    *(uint2*)&att[((size_t)b * T_ + qrow) * 1024 + h0 * 64 + lm * 4] = st;
    const float inv1 = 1.f / lacc1[r];
    st.x = pk2(oacc1[0][r] * inv1, oacc1[1][r] * inv1);
    st.y = pk2(oacc1[2][r] * inv1, oacc1[3][r] * inv1);
    *(uint2*)&att[((size_t)b * T_ + qrow) * 1024 + h1 * 64 + lm * 4] = st;
  }
}

// ---------------------------------------------------------------------------
// Kernel 3: output projection, 128x64 tiles, BK=128 (8 k-iters), grid 512
// 1-D blocks, XCD-chunked mapping. Same global_load_lds staging + XOR
// swizzle as kernel 1. bf16 in (slot-permuted k-dim, matched by WoT),
// fp32 out. [UNCHANGED from round 3]
// ---------------------------------------------------------------------------
__global__ __launch_bounds__(256) void outproj_mfma_kernel(
    const short* __restrict__ att, const short* __restrict__ WoT,
    float* __restrict__ out) {
  __shared__ short Xs[128 * 128];
  __shared__ short Wt[64 * 128];
  const int tid = threadIdx.x;
  const int lane = tid & 63, w = tid >> 6;
  const int lm = lane & 15, quad = lane >> 4;
  const int lr = lane >> 4;
  const int lb = lane & 15;
  // XCD-chunked decode: 512 = 8 XCDs x (4 m x 16 n)
  const int bid = blockIdx.x;
  const int xcd = bid & 7, slot = bid >> 3;     // slot 0..63
  const int m0 = (xcd * 4 + (slot & 3)) * 128;
  const int n0 = (slot >> 2) * 64;              // 0..960

  f32x4 acc[2][4];
  #pragma unroll
  for (int sm = 0; sm < 2; ++sm)
    #pragma unroll
    for (int ct = 0; ct < 4; ++ct) acc[sm][ct] = (f32x4){0.f, 0.f, 0.f, 0.f};

  for (int kt = 0; kt < 8; ++kt) {
    __syncthreads();
    #pragma unroll
    for (int u = 0; u < 8; ++u) {
      const int r = (w * 8 + u) * 4 + lr;
      const int sb = lb ^ (r & 7);
      g2l16(&att[(size_t)(m0 + r) * 1024 + kt * 128 + sb * 8],
            &Xs[(w * 8 + u) * 512]);
    }
    #pragma unroll
    for (int u = 0; u < 4; ++u) {
      const int r = (w * 4 + u) * 4 + lr;
      const int sb = lb ^ (r & 7);
      g2l16(&WoT[(size_t)(n0 + r) * 1024 + kt * 128 + sb * 8],
            &Wt[(w * 4 + u) * 512]);
    }
    asm volatile("s_waitcnt vmcnt(0)" ::: "memory");
    __syncthreads();
    #pragma unroll
    for (int s = 0; s < 4; ++s) {
      bf16x8 bfr[4];
      #pragma unroll
      for (int ct = 0; ct < 4; ++ct)
        bfr[ct] = *(const bf16x8*)&Wt[(ct * 16 + lm) * 128 +
                                      (((s * 4 + quad) ^ (lm & 7)) << 3)];
      #pragma unroll
      for (int sm = 0; sm < 2; ++sm) {
        const bf16x8 a = *(const bf16x8*)&Xs[(w * 32 + sm * 16 + lm) * 128 +
                                             (((s * 4 + quad) ^ (lm & 7)) << 3)];
        #pragma unroll
        for (int ct = 0; ct < 4; ++ct)
          acc[sm][ct] =
              __builtin_amdgcn_mfma_f32_16x16x32_bf16(a, bfr[ct], acc[sm][ct], 0, 0, 0);
      }
    }
  }

  #pragma unroll
  for (int sm = 0; sm < 2; ++sm)
    #pragma unroll
    for (int r = 0; r < 4; ++r) {
      const int row = m0 + w * 32 + sm * 16 + quad * 4 + r;
      #pragma unroll
      for (int ct = 0; ct < 4; ++ct)
        out[(size_t)row * 1024 + n0 + ct * 16 + lm] = acc[sm][ct][r];
    }
}

extern "C" void kernel_launch(void* const* d_in, const int* in_sizes, int n_in,
                              void* d_out, int out_size, void* d_ws, size_t ws_size,
                              hipStream_t stream) {
  const float* x  = (const float*)d_in[0];
  // d_in[1] = mask: fixed causal tril, handled analytically; never read.
  const float* Wq = (const float*)d_in[2];
  const float* Wk = (const float*)d_in[3];
  const float* Wv = (const float*)d_in[4];
  const float* Wo = (const float*)d_in[5];
  float* out = (float*)d_out;

  // ws carve (bf16 shorts unless noted): xb 8.4MB | WT 3.1MB | WoT 2.1MB |
  // q 8.4MB | k 2.1MB | vt 2.1MB | att 8.4MB | rope tbl 0.5MB  ~= 35.1MB
  short* xb   = (short*)d_ws;
  short* WT   = xb  + (size_t)4194304;          // 1536*1024
  short* WoT  = WT  + (size_t)1572864;          // 1024*1024 (k sigma-permuted)
  short* qb   = WoT + (size_t)1048576;          // 2*16*2048*64 (d sigma-permuted)
  short* kb   = qb  + (size_t)4194304;          // 2*4*2048*64 (d sigma-permuted)
  short* vtb  = kb  + (size_t)1048576;          // 2*4*64*2048 (transposed+permuted)
  short* attb = vtb + (size_t)1048576;          // 2*2048*1024 (d sigma-permuted)
  float2* tbl = (float2*)(attb + (size_t)4194304);  // 2048*32 float2

  prep_kernel<<<dim3(2944), dim3(256), 0, stream>>>(
      x, Wq, Wk, Wv, Wo, xb, WT, WoT, tbl);
  qkv_mfma_kernel<<<dim3(768), dim3(256), 0, stream>>>(xb, WT, tbl, qb, kb, vtb);
  attn_mfma_kernel<<<dim3(512), dim3(256), 0, stream>>>(qb, kb, vtb, attb);
  outproj_mfma_kernel<<<dim3(512), dim3(256), 0, stream>>>(attb, WoT, out);
}

// Round 6
// 168.618 us; speedup vs baseline: 1.0613x; 1.0613x over previous
//
#include <hip/hip_runtime.h>
#include <hip/hip_bf16.h>

#define B_  2
#define T_  2048
#define D_  1024
#define H_  16
#define KH_ 4
#define DH_ 64

typedef __attribute__((ext_vector_type(8))) short bf16x8;   // 8 bf16 = 4 VGPRs
typedef __attribute__((ext_vector_type(4))) float f32x4;

// log2(e)/8: folded into Q at projection time so softmax is p = exp2(s_raw).
#define QSCALE 0.18033688011112043f

// single-instruction v_exp_f32 if available (OCML exp2f is ~10 instrs)
#if defined(__has_builtin)
#  if __has_builtin(__builtin_amdgcn_exp2f)
#    define EXP2F(x) __builtin_amdgcn_exp2f(x)
#  endif
#endif
#ifndef EXP2F
#  define EXP2F(x) exp2f(x)
#endif

// fp32 -> bf16 RNE (scalar, for prep paths where cvt_pk doesn't fit)
__device__ __forceinline__ unsigned short f2bf(float f) {
  union { float f; unsigned int u; } v; v.f = f;
  return (unsigned short)((v.u + 0x7FFFu + ((v.u >> 16) & 1u)) >> 16);
}
// packed fp32x2 -> bf16x2 via v_cvt_pk_bf16_f32 (1 VALU op)
__device__ __forceinline__ unsigned int pk2(float a, float b) {
  union { __hip_bfloat162 h2; unsigned int u; } v;
  v.h2 = __float22bfloat162_rn(make_float2(a, b));
  return v.u;
}

// async global->LDS, 16B per lane. LDS dest = wave-uniform base + lane*16;
// global source is per-lane (pre-swizzled source pattern, m173/rule #21).
__device__ __forceinline__ void g2l16(const void* g, void* l) {
  __builtin_amdgcn_global_load_lds(
      (const __attribute__((address_space(1))) void*)g,
      (__attribute__((address_space(3))) void*)l, 16, 0, 0);
}

// d-slot permutation: slot(d) = (d&15)*4 + (d>>4). Applied consistently to
// Q/K d-dims (QK contraction invariant), att per-head d-dim + WoT k-rows
// (outproj contraction invariant). Exact.
//
// V key-slot permutation (attn swapped-QK in-register P): slot g (0..63)
// holds key tok(g) with bit map  tok5<-g5, tok4<-g2, tok3:2<-g4:3,
// tok1:0<-g1:0.  This makes the PV A-operand buildable from each lane's OWN
// exp'd QK outputs (no cross-lane exchange, no P LDS bounce).

// ---------------------------------------------------------------------------
// Merged prep (one launch): x->bf16, Wqkv->WT (bf16 transposed),
// Wo->WoT (bf16 transposed, k-rows sigma-permuted per head), RoPE table.
// [UNCHANGED]
// ---------------------------------------------------------------------------
__global__ __launch_bounds__(256) void prep_kernel(
    const float* __restrict__ x,  const float* __restrict__ Wq,
    const float* __restrict__ Wk, const float* __restrict__ Wv,
    const float* __restrict__ Wo,
    short* __restrict__ xb, short* __restrict__ WT, short* __restrict__ WoT,
    float2* __restrict__ tbl) {
  __shared__ short Ts[64 * 72];
  const int bid = blockIdx.x, tid = threadIdx.x;

  if (bid < 2048) {                             // ---- x -> bf16
    const size_t i8 = ((size_t)bid * 256 + tid) * 8;
    const float4 a = *(const float4*)&x[i8];
    const float4 b = *(const float4*)&x[i8 + 4];
    uint4 p; p.x = pk2(a.x, a.y); p.y = pk2(a.z, a.w);
    p.z = pk2(b.x, b.y); p.w = pk2(b.z, b.w);
    *(uint4*)&xb[i8] = p;
  } else if (bid < 2688) {                      // ---- WT / WoT transpose
    const bool isW = bid < 2432;
    const int idx = isW ? (bid - 2048) : (bid - 2432);
    const int n0 = (idx >> 4) * 64, k0 = (idx & 15) * 64;
    const float* src; int ncols, c0; short* dst;
    if (isW) {
      dst = WT;
      if (n0 < 1024)      { src = Wq; ncols = 1024; c0 = n0; }
      else if (n0 < 1280) { src = Wk; ncols = 256;  c0 = n0 - 1024; }
      else                { src = Wv; ncols = 256;  c0 = n0 - 1280; }
    } else { dst = WoT; src = Wo; ncols = 1024; c0 = n0; }
    for (int i = tid; i < 1024; i += 256) {
      const int kr = i >> 4, c4 = (i & 15) << 2;
      // WoT k-rows permuted: slot(kr) = (kr&15)*4 + (kr>>4) (k0 is 64-aligned
      // = one head's range, so per-head sigma).
      const int kc = isW ? kr : ((kr & 15) * 4 + (kr >> 4));
      const float4 w = *(const float4*)&src[(size_t)(k0 + kr) * ncols + c0 + c4];
      Ts[(c4 + 0) * 72 + kc] = (short)f2bf(w.x);
      Ts[(c4 + 1) * 72 + kc] = (short)f2bf(w.y);
      Ts[(c4 + 2) * 72 + kc] = (short)f2bf(w.z);
      Ts[(c4 + 3) * 72 + kc] = (short)f2bf(w.w);
    }
    __syncthreads();
    for (int c = tid; c < 512; c += 256) {
      const int nr = c >> 3, c8 = (c & 7) * 8;
      *(bf16x8*)&dst[(size_t)(n0 + nr) * 1024 + k0 + c8] =
          *(const bf16x8*)&Ts[nr * 72 + c8];
    }
  } else {                                      // ---- RoPE table
    const int e = (bid - 2688) * 256 + tid;     // 65536 entries
    const int t = e >> 5, i2 = e & 31;
    const float freq = exp2f(-(float)(2 * i2) * (18.931568569324174f / 64.0f));
    float sn, cs; sincosf((float)t * freq, &sn, &cs);
    tbl[e] = make_float2(cs, sn);
  }
}

// ---------------------------------------------------------------------------
// Kernel 1: QKV projection, 128x64 tiles, T3-minimum 2-PHASE double-buffered
// K-loop: BK=64, 16 kt iters; per iter issue next tile's 6 g2l16, then
// COUNTED s_waitcnt vmcnt(6) (never 0 mid-loop) + raw s_barrier -> loads
// have a full compute phase to land (was: vmcnt(0)+__syncthreads full drain
// per kt = 8 serialized HBM round-trips/block, the m97 ~20%+ stall).
// LDS 2x(16K+8K) = 48KB -> 3 blocks/CU. XOR block swizzle kept (8 blocks/row,
// blk ^= row&7; source-side pre-swizzle, rule #21). XCD-chunked grid 768.
// nt<16: Q (RoPE + QSCALE fold). 16..19: K (RoPE). 20..23: V (LDS-bounce
// transpose -> (b,kh,d,t), key slots permuted per attn's in-register-P map).
// ---------------------------------------------------------------------------
__global__ __launch_bounds__(256) void qkv_mfma_kernel(
    const short* __restrict__ xb, const short* __restrict__ WT,
    const float2* __restrict__ tbl,
    short* __restrict__ qo, short* __restrict__ ko, short* __restrict__ vt) {
  __shared__ short Xsh[2][128 * 64];
  __shared__ short Wth[2][64 * 64];
  const int tid = threadIdx.x;
  const int lane = tid & 63, w = tid >> 6;
  const int lm = lane & 15, quad = lane >> 4;
  // XCD-chunked decode: 768 = 8 XCDs x (4 m x 24 n)
  const int bid = blockIdx.x;
  const int xcd = bid & 7, slot = bid >> 3;     // slot 0..95
  const int m0 = (xcd * 4 + (slot & 3)) * 128;  // 0..3968
  const int n0 = (slot >> 2) * 64;              // 0..1472

  f32x4 acc[2][4];
  #pragma unroll
  for (int sm = 0; sm < 2; ++sm)
    #pragma unroll
    for (int ct = 0; ct < 4; ++ct) acc[sm][ct] = (f32x4){0.f, 0.f, 0.f, 0.f};

  // stage one BK=64 tile pair into buffer bsel (6 g2l16 per wave)
  auto stage = [&](int kt, int bsel) {
    #pragma unroll
    for (int u = 0; u < 4; ++u) {               // Xs: 128 rows, 8 rows/call
      const int r = u * 32 + w * 8 + (lane >> 3);
      const int sb = (lane & 7) ^ (r & 7);      // inverse-swizzled source blk
      g2l16(&xb[(size_t)(m0 + r) * 1024 + kt * 64 + sb * 8],
            &Xsh[bsel][(u * 32 + w * 8) * 64]);
    }
    #pragma unroll
    for (int u = 0; u < 2; ++u) {               // Wt: 64 rows
      const int r = u * 32 + w * 8 + (lane >> 3);
      const int sb = (lane & 7) ^ (r & 7);
      g2l16(&WT[(size_t)(n0 + r) * 1024 + kt * 64 + sb * 8],
            &Wth[bsel][(u * 32 + w * 8) * 64]);
    }
  };

  stage(0, 0);                                  // prologue
  for (int kt = 0; kt < 16; ++kt) {
    const int bsel = kt & 1;
    if (kt < 15) {
      stage(kt + 1, bsel ^ 1);                  // issue-early: flies w/ compute
      asm volatile("s_waitcnt vmcnt(6)" ::: "memory");  // cur tile landed
    } else {
      asm volatile("s_waitcnt vmcnt(0)" ::: "memory");
    }
    __builtin_amdgcn_s_barrier();               // all waves' cur data in LDS
    __builtin_amdgcn_sched_barrier(0);
    #pragma unroll
    for (int s2 = 0; s2 < 2; ++s2) {            // 2 k-steps of 32
      bf16x8 bfr[4];
      #pragma unroll
      for (int ct = 0; ct < 4; ++ct)
        bfr[ct] = *(const bf16x8*)&Wth[bsel][(ct * 16 + lm) * 64 +
                                            (((s2 * 4 + quad) ^ (lm & 7)) << 3)];
      #pragma unroll
      for (int sm = 0; sm < 2; ++sm) {
        const bf16x8 a = *(const bf16x8*)&Xsh[bsel][(w * 32 + sm * 16 + lm) * 64 +
                                            (((s2 * 4 + quad) ^ (lm & 7)) << 3)];
        #pragma unroll
        for (int ct = 0; ct < 4; ++ct)
          acc[sm][ct] =
              __builtin_amdgcn_mfma_f32_16x16x32_bf16(a, bfr[ct], acc[sm][ct], 0, 0, 0);
      }
    }
    __builtin_amdgcn_sched_barrier(0);
    __builtin_amdgcn_s_barrier();               // reads done before re-stage
  }

  if (n0 < 1280) {                              // ---- Q or K: RoPE + b64 store
    const bool isQ = n0 < 1024;
    short* outp = isQ ? qo : ko;
    const int base = isQ ? n0 : n0 - 1024;
    const int nh = isQ ? H_ : KH_;
    const int hh = base >> 6;                   // tile width 64 = one head
    const float post = isQ ? QSCALE : 1.0f;     // fold softmax scale into Q
    #pragma unroll
    for (int sm = 0; sm < 2; ++sm)
      #pragma unroll
      for (int r = 0; r < 4; ++r) {
        const int row = m0 + w * 32 + sm * 16 + quad * 4 + r;
        const int b = row >> 11, t = row & 2047;
        float v4[4];
        #pragma unroll
        for (int ct = 0; ct < 4; ++ct) {
          float val = acc[sm][ct][r];
          const float other = __shfl_xor(val, 1);
          const int ci = ct * 16 + lm;          // d within head
          const float2 cs = tbl[t * 32 + (ci >> 1)];
          val = ((ci & 1) == 0) ? (val * cs.x - other * cs.y)
                                : (val * cs.x + other * cs.y);
          v4[ct] = val * post;
        }
        // d ct*16+lm -> slot lm*4+ct: one b64 store of 4 consecutive slots
        uint2 st; st.x = pk2(v4[0], v4[1]); st.y = pk2(v4[2], v4[3]);
        *(uint2*)&outp[((size_t)(b * nh + hh) * T_ + t) * DH_ + lm * 4] = st;
      }
  } else {                                      // ---- V: LDS-bounce transpose
    short* XsF = &Xsh[0][0];                    // 16384 shorts scratch
    __syncthreads();                            // done with LDS as GEMM tiles
    #pragma unroll
    for (int sm = 0; sm < 2; ++sm)
      #pragma unroll
      for (int r = 0; r < 4; ++r)
        #pragma unroll
        for (int ct = 0; ct < 4; ++ct)
          XsF[(w * 32 + sm * 16 + quad * 4 + r) * 72 + ct * 16 + lm] =
              (short)f2bf(acc[sm][ct][r]);      // [t][d], stride 72 region
    __syncthreads();
    const int kh = (n0 - 1280) >> 6;
    const int b = m0 >> 11, t0 = m0 & 2047;
    short* vb = vt + (size_t)(b * KH_ + kh) * DH_ * T_;
    for (int c = tid; c < 1024; c += 256) {     // 64 d-rows x 16 chunks of 8 slots
      const int d = c >> 4, c8 = (c & 15) * 8;
      short tmp[8];
      #pragma unroll
      for (int j = 0; j < 8; ++j) {
        const int s = c8 + j, sg = s & 63;      // slot s -> token within group
        // tok bits: b5<-g5, b4<-g2, b3:2<-g4:3, b1:0<-g1:0 (in-reg P map)
        const int tok = (s & 64) | (sg & 35) | (((sg >> 2) & 1) << 4) |
                        (((sg >> 3) & 3) << 2);
        tmp[j] = XsF[tok * 72 + d];
      }
      *(bf16x8*)&vb[(size_t)d * T_ + t0 + c8] = *(bf16x8*)tmp;
    }
  }
}

// ---------------------------------------------------------------------------
// Kernel 2: causal flash attention, swapped-QK in-register-P structure
// [round-3 grid/balance: one head/block, 1024 blocks = 4/CU — round 4
// proved attn is latency-bound per-wave] + PAIR-INTERLEAVE:
// QK0->QK1->SM0->PV0->SM1->PV1. QK1 (indep of SM0/PV0) fills sacc0's MFMA
// latency window; PV0's MFMAs fly under SM1's VALU. Register-only
// reordering of the verified ops. Grid 1024, qt interleave = constant 66
// steps/CU; diag tiles skip masked MFMA blocks (wave-uniform); row-sum via
// MFMA ones-column; reg prefetch for K/V; s_setprio(1) around MFMA
// clusters (T5).
// ---------------------------------------------------------------------------
__global__ __launch_bounds__(256, 4) void attn_mfma_kernel(
    const short* __restrict__ q, const short* __restrict__ k,
    const short* __restrict__ vt, short* __restrict__ att) {
  __shared__ short Ks[128 * 72];
  __shared__ short Vts[64 * 136];               // [d][slot 0..127]

  const int bx = blockIdx.x;
  const int jj = bx & 255, c2 = bx >> 8;
  int qt = (c2 & 1) ? (jj >> 3) : (31 - (jj >> 3));   // heavy-first in chunk 0
  const int hb = (jj & 7) | (c2 << 3);
  const int h = hb >> 1, b = hb & 1;
  const int kh = h >> 2;                        // n_rep = 4
  const int tid = threadIdx.x;
  const int lane = tid & 63, w = tid >> 6;
  const int lm = lane & 15, quad = lane >> 4;
  const int q0 = qt * 64;

  const short* qb = q + (size_t)(b * H_ + h) * T_ * DH_;
  const short* kb = k + (size_t)(b * KH_ + kh) * T_ * DH_;
  const short* vb = vt + (size_t)(b * KH_ + kh) * DH_ * T_;

  bf16x8 ones;
  #pragma unroll
  for (int i = 0; i < 8; ++i) ones[i] = (short)0x3F80;  // bf16 1.0

  bf16x8 aq[2];                                 // kt-invariant Q fragments
  #pragma unroll
  for (int s = 0; s < 2; ++s)                   // direct global load (no LDS)
    aq[s] = *(const bf16x8*)&qb[(size_t)(q0 + w * 16 + lm) * 64 + s * 32 + quad * 8];

  bf16x8 pk[4], pv[4];
  #pragma unroll
  for (int u = 0; u < 4; ++u) {                 // preload r2=0 (128 keys)
    const int c = tid + u * 256;
    const int row = c >> 3, c8 = (c & 7) * 8;
    pk[u] = *(const bf16x8*)&kb[(size_t)row * 64 + c8];
    const int d = c >> 4, c16 = (c & 15) * 8;
    pv[u] = *(const bf16x8*)&vb[(size_t)d * T_ + c16];
  }

  f32x4 oacc[4], lacc;
  #pragma unroll
  for (int i = 0; i < 4; ++i) oacc[i] = (f32x4){0.f, 0.f, 0.f, 0.f};
  lacc = (f32x4){0.f, 0.f, 0.f, 0.f};

  // interleaved 128-key pair: QK0, QK1, SM0, PV0, SM1, PV1
  auto pairstep = [&](bool diag1) {
    f32x4 sacc0[4], sacc1[4];
    #pragma unroll
    for (int i = 0; i < 4; ++i) {
      sacc0[i] = (f32x4){0.f, 0.f, 0.f, 0.f};
      sacc1[i] = (f32x4){0.f, 0.f, 0.f, 0.f};
    }
    __builtin_amdgcn_s_setprio(1);
    #pragma unroll
    for (int s2 = 0; s2 < 2; ++s2)              // QK0 (never diagonal)
      #pragma unroll
      for (int ct = 0; ct < 4; ++ct) {
        const bf16x8 bb =
            *(const bf16x8*)&Ks[(ct * 16 + lm) * 72 + s2 * 32 + quad * 8];
        sacc0[ct] = __builtin_amdgcn_mfma_f32_16x16x32_bf16(bb, aq[s2], sacc0[ct], 0, 0, 0);
      }
    #pragma unroll
    for (int s2 = 0; s2 < 2; ++s2)              // QK1 (fills sacc0 latency)
      #pragma unroll
      for (int ct = 0; ct < 4; ++ct) {
        if (diag1 && ct > w) continue;          // fully-masked block, skip
        const bf16x8 bb =
            *(const bf16x8*)&Ks[(64 + ct * 16 + lm) * 72 + s2 * 32 + quad * 8];
        sacc1[ct] = __builtin_amdgcn_mfma_f32_16x16x32_bf16(bb, aq[s2], sacc1[ct], 0, 0, 0);
      }
    __builtin_amdgcn_s_setprio(0);
    // SM0: sacc0[ct][r] = P[key ct*16+quad*4+r][q w*16+lm]
    unsigned int pd0[4][2];
    #pragma unroll
    for (int ct = 0; ct < 4; ++ct) {
      float p[4];
      #pragma unroll
      for (int r = 0; r < 4; ++r) p[r] = EXP2F(sacc0[ct][r]);
      pd0[ct][0] = pk2(p[0], p[1]); pd0[ct][1] = pk2(p[2], p[3]);
    }
    __builtin_amdgcn_s_setprio(1);
    #pragma unroll
    for (int s2 = 0; s2 < 2; ++s2) {            // PV0
      union { bf16x8 v; unsigned int u[4]; } pa;
      pa.u[0] = pd0[2 * s2][0];     pa.u[1] = pd0[2 * s2][1];
      pa.u[2] = pd0[2 * s2 + 1][0]; pa.u[3] = pd0[2 * s2 + 1][1];
      lacc = __builtin_amdgcn_mfma_f32_16x16x32_bf16(pa.v, ones, lacc, 0, 0, 0);
      #pragma unroll
      for (int ct = 0; ct < 4; ++ct) {
        const bf16x8 vfr = *(const bf16x8*)&Vts[(ct * 16 + lm) * 136 +
                                                s2 * 32 + quad * 8];
        oacc[ct] = __builtin_amdgcn_mfma_f32_16x16x32_bf16(pa.v, vfr, oacc[ct], 0, 0, 0);
      }
    }
    __builtin_amdgcn_s_setprio(0);
    // SM1 (flies under PV0's MFMAs)
    unsigned int pd1[4][2];
    #pragma unroll
    for (int ct = 0; ct < 4; ++ct) {
      float p[4];
      #pragma unroll
      for (int r = 0; r < 4; ++r) {
        float e;
        if (diag1 && ct > w) e = 0.f;           // block fully above diagonal
        else {
          e = EXP2F(sacc1[ct][r]);
          if (diag1 && ct == w && (quad * 4 + r) > lm) e = 0.f;  // causal mask
        }
        p[r] = e;
      }
      pd1[ct][0] = pk2(p[0], p[1]); pd1[ct][1] = pk2(p[2], p[3]);
    }
    __builtin_amdgcn_s_setprio(1);
    #pragma unroll
    for (int s2 = 0; s2 < 2; ++s2) {            // PV1
      if (diag1 && 2 * s2 > w) continue;        // both ct' blocks masked
      union { bf16x8 v; unsigned int u[4]; } pa;
      pa.u[0] = pd1[2 * s2][0];     pa.u[1] = pd1[2 * s2][1];
      pa.u[2] = pd1[2 * s2 + 1][0]; pa.u[3] = pd1[2 * s2 + 1][1];
      lacc = __builtin_amdgcn_mfma_f32_16x16x32_bf16(pa.v, ones, lacc, 0, 0, 0);
      #pragma unroll
      for (int ct = 0; ct < 4; ++ct) {
        const bf16x8 vfr = *(const bf16x8*)&Vts[(ct * 16 + lm) * 136 +
                                                64 + s2 * 32 + quad * 8];
        oacc[ct] = __builtin_amdgcn_mfma_f32_16x16x32_bf16(pa.v, vfr, oacc[ct], 0, 0, 0);
      }
    }
    __builtin_amdgcn_s_setprio(0);
  };

  // peeled single 64-key diagonal step (j=0)
  auto dstep = [&]() {
    f32x4 sacc[4];
    #pragma unroll
    for (int i = 0; i < 4; ++i) sacc[i] = (f32x4){0.f, 0.f, 0.f, 0.f};
    __builtin_amdgcn_s_setprio(1);
    #pragma unroll
    for (int s2 = 0; s2 < 2; ++s2)
      #pragma unroll
      for (int ct = 0; ct < 4; ++ct) {
        if (ct > w) continue;
        const bf16x8 bb =
            *(const bf16x8*)&Ks[(ct * 16 + lm) * 72 + s2 * 32 + quad * 8];
        sacc[ct] = __builtin_amdgcn_mfma_f32_16x16x32_bf16(bb, aq[s2], sacc[ct], 0, 0, 0);
      }
    __builtin_amdgcn_s_setprio(0);
    unsigned int pd[4][2];
    #pragma unroll
    for (int ct = 0; ct < 4; ++ct) {
      float p[4];
      #pragma unroll
      for (int r = 0; r < 4; ++r) {
        float e;
        if (ct > w) e = 0.f;
        else {
          e = EXP2F(sacc[ct][r]);
          if (ct == w && (quad * 4 + r) > lm) e = 0.f;
        }
        p[r] = e;
      }
      pd[ct][0] = pk2(p[0], p[1]); pd[ct][1] = pk2(p[2], p[3]);
    }
    __builtin_amdgcn_s_setprio(1);
    #pragma unroll
    for (int s2 = 0; s2 < 2; ++s2) {
      if (2 * s2 > w) continue;
      union { bf16x8 v; unsigned int u[4]; } pa;
      pa.u[0] = pd[2 * s2][0];     pa.u[1] = pd[2 * s2][1];
      pa.u[2] = pd[2 * s2 + 1][0]; pa.u[3] = pd[2 * s2 + 1][1];
      lacc = __builtin_amdgcn_mfma_f32_16x16x32_bf16(pa.v, ones, lacc, 0, 0, 0);
      #pragma unroll
      for (int ct = 0; ct < 4; ++ct) {
        const bf16x8 vfr = *(const bf16x8*)&Vts[(ct * 16 + lm) * 136 +
                                                s2 * 32 + quad * 8];
        oacc[ct] = __builtin_amdgcn_mfma_f32_16x16x32_bf16(pa.v, vfr, oacc[ct], 0, 0, 0);
      }
    }
    __builtin_amdgcn_s_setprio(0);
  };

  auto stage = [&](int r2) {
    __syncthreads();                            // prior K/V LDS reads done
    #pragma unroll
    for (int u = 0; u < 4; ++u) {
      const int c = tid + u * 256;
      const int row = c >> 3, c8 = (c & 7) * 8;
      *(bf16x8*)&Ks[row * 72 + c8] = pk[u];
      const int d = c >> 4, c16 = (c & 15) * 8;
      *(bf16x8*)&Vts[d * 136 + c16] = pv[u];
    }
    __syncthreads();
    const int r2n = (r2 + 2 <= qt) ? (r2 + 2) : r2;   // prefetch next pair
    #pragma unroll
    for (int u = 0; u < 4; ++u) {
      const int c = tid + u * 256;
      const int row = c >> 3, c8 = (c & 7) * 8;
      pk[u] = *(const bf16x8*)&kb[(size_t)(r2n * 64 + row) * 64 + c8];
      const int d = c >> 4, c16 = (c & 15) * 8;
      pv[u] = *(const bf16x8*)&vb[(size_t)d * T_ + r2n * 64 + c16];
    }
  };

  int r2 = 0;
  for (; r2 + 1 <= qt; r2 += 2) {               // full pairs only
    stage(r2);
    pairstep(r2 + 1 == qt);                     // diag only on last pair's j=1
  }
  if (r2 == qt) {                               // peeled final step (even qt)
    stage(r2);
    dstep();
  }

  #pragma unroll
  for (int r = 0; r < 4; ++r) {
    const int qrow = q0 + w * 16 + quad * 4 + r;
    const float inv = 1.f / lacc[r];
    // d ct*16+lm -> slot lm*4+ct (WoT k-rows match): one b64 store
    uint2 st;
    st.x = pk2(oacc[0][r] * inv, oacc[1][r] * inv);
    st.y = pk2(oacc[2][r] * inv, oacc[3][r] * inv);
    *(uint2*)&att[((size_t)b * T_ + qrow) * 1024 + h * 64 + lm * 4] = st;
  }
}

// ---------------------------------------------------------------------------
// Kernel 3: output projection, 128x64 tiles, same 2-phase BK=64 double-
// buffered counted-vmcnt loop as kernel 1. Grid 512 XCD-chunked. bf16 in
// (slot-permuted k-dim, matched by WoT), fp32 out.
// ---------------------------------------------------------------------------
__global__ __launch_bounds__(256) void outproj_mfma_kernel(
    const short* __restrict__ att, const short* __restrict__ WoT,
    float* __restrict__ out) {
  __shared__ short Xsh[2][128 * 64];
  __shared__ short Wth[2][64 * 64];
  const int tid = threadIdx.x;
  const int lane = tid & 63, w = tid >> 6;
  const int lm = lane & 15, quad = lane >> 4;
  // XCD-chunked decode: 512 = 8 XCDs x (4 m x 16 n)
  const int bid = blockIdx.x;
  const int xcd = bid & 7, slot = bid >> 3;     // slot 0..63
  const int m0 = (xcd * 4 + (slot & 3)) * 128;
  const int n0 = (slot >> 2) * 64;              // 0..960

  f32x4 acc[2][4];
  #pragma unroll
  for (int sm = 0; sm < 2; ++sm)
    #pragma unroll
    for (int ct = 0; ct < 4; ++ct) acc[sm][ct] = (f32x4){0.f, 0.f, 0.f, 0.f};

  auto stage = [&](int kt, int bsel) {
    #pragma unroll
    for (int u = 0; u < 4; ++u) {
      const int r = u * 32 + w * 8 + (lane >> 3);
      const int sb = (lane & 7) ^ (r & 7);
      g2l16(&att[(size_t)(m0 + r) * 1024 + kt * 64 + sb * 8],
            &Xsh[bsel][(u * 32 + w * 8) * 64]);
    }
    #pragma unroll
    for (int u = 0; u < 2; ++u) {
      const int r = u * 32 + w * 8 + (lane >> 3);
      const int sb = (lane & 7) ^ (r & 7);
      g2l16(&WoT[(size_t)(n0 + r) * 1024 + kt * 64 + sb * 8],
            &Wth[bsel][(u * 32 + w * 8) * 64]);
    }
  };

  stage(0, 0);
  for (int kt = 0; kt < 16; ++kt) {
    const int bsel = kt & 1;
    if (kt < 15) {
      stage(kt + 1, bsel ^ 1);
      asm volatile("s_waitcnt vmcnt(6)" ::: "memory");
    } else {
      asm volatile("s_waitcnt vmcnt(0)" ::: "memory");
    }
    __builtin_amdgcn_s_barrier();
    __builtin_amdgcn_sched_barrier(0);
    #pragma unroll
    for (int s2 = 0; s2 < 2; ++s2) {
      bf16x8 bfr[4];
      #pragma unroll
      for (int ct = 0; ct < 4; ++ct)
        bfr[ct] = *(const bf16x8*)&Wth[bsel][(ct * 16 + lm) * 64 +
                                            (((s2 * 4 + quad) ^ (lm & 7)) << 3)];
      #pragma unroll
      for (int sm = 0; sm < 2; ++sm) {
        const bf16x8 a = *(const bf16x8*)&Xsh[bsel][(w * 32 + sm * 16 + lm) * 64 +
                                            (((s2 * 4 + quad) ^ (lm & 7)) << 3)];
        #pragma unroll
        for (int ct = 0; ct < 4; ++ct)
          acc[sm][ct] =
              __builtin_amdgcn_mfma_f32_16x16x32_bf16(a, bfr[ct], acc[sm][ct], 0, 0, 0);
      }
    }
    __builtin_amdgcn_sched_barrier(0);
    __builtin_amdgcn_s_barrier();
  }

  #pragma unroll
  for (int sm = 0; sm < 2; ++sm)
    #pragma unroll
    for (int r = 0; r < 4; ++r) {
      const int row = m0 + w * 32 + sm * 16 + quad * 4 + r;
      #pragma unroll
      for (int ct = 0; ct < 4; ++ct)
        out[(size_t)row * 1024 + n0 + ct * 16 + lm] = acc[sm][ct][r];
    }
}

extern "C" void kernel_launch(void* const* d_in, const int* in_sizes, int n_in,
                              void* d_out, int out_size, void* d_ws, size_t ws_size,
                              hipStream_t stream) {
  const float* x  = (const float*)d_in[0];
  // d_in[1] = mask: fixed causal tril, handled analytically; never read.
  const float* Wq = (const float*)d_in[2];
  const float* Wk = (const float*)d_in[3];
  const float* Wv = (const float*)d_in[4];
  const float* Wo = (const float*)d_in[5];
  float* out = (float*)d_out;

  // ws carve (bf16 shorts unless noted): xb 8.4MB | WT 3.1MB | WoT 2.1MB |
  // q 8.4MB | k 2.1MB | vt 2.1MB | att 8.4MB | rope tbl 0.5MB  ~= 35.1MB
  short* xb   = (short*)d_ws;
  short* WT   = xb  + (size_t)4194304;          // 1536*1024
  short* WoT  = WT  + (size_t)1572864;          // 1024*1024 (k sigma-permuted)
  short* qb   = WoT + (size_t)1048576;          // 2*16*2048*64 (d sigma-permuted)
  short* kb   = qb  + (size_t)4194304;          // 2*4*2048*64 (d sigma-permuted)
  short* vtb  = kb  + (size_t)1048576;          // 2*4*64*2048 (transposed+permuted)
  short* attb = vtb + (size_t)1048576;          // 2*2048*1024 (d sigma-permuted)
  float2* tbl = (float2*)(attb + (size_t)4194304);  // 2048*32 float2

  prep_kernel<<<dim3(2944), dim3(256), 0, stream>>>(
      x, Wq, Wk, Wv, Wo, xb, WT, WoT, tbl);
  qkv_mfma_kernel<<<dim3(768), dim3(256), 0, stream>>>(xb, WT, tbl, qb, kb, vtb);
  attn_mfma_kernel<<<dim3(1024), dim3(256), 0, stream>>>(qb, kb, vtb, attb);
  outproj_mfma_kernel<<<dim3(512), dim3(256), 0, stream>>>(attb, WoT, out);
}